// Round 1
// baseline (202.177 us; speedup 1.0000x reference)
//
#include <hip/hip_runtime.h>
#include <cstdint>
#include <cstddef>

typedef __bf16 bf16x8 __attribute__((ext_vector_type(8)));
typedef __bf16 bf16x2v __attribute__((ext_vector_type(2)));
typedef unsigned short u16;
typedef u16 u16x8v __attribute__((ext_vector_type(8)));
typedef float  f32x4  __attribute__((ext_vector_type(4)));
typedef unsigned int u32;

#define MFMA16(a, b, c) __builtin_amdgcn_mfma_f32_16x16x32_bf16((a), (b), (c), 0, 0, 0)
#define ASYNC16(g, l)                                                              \
  __builtin_amdgcn_global_load_lds(                                                \
      (const __attribute__((address_space(1))) unsigned int*)(g),                  \
      (__attribute__((address_space(3))) unsigned int*)(l), 16, 0, 0)

__device__ __forceinline__ u16 f2bf(float f) {
  unsigned u = __builtin_bit_cast(unsigned, f);
  u += 0x7fffu + ((u >> 16) & 1u);
  return (u16)(u >> 16);
}

// packed fp32x2 -> bf16x2 (RNE) via hardware cvt
__device__ __forceinline__ u32 cvt2(float a, float b) {
  bf16x2v t;
  t[0] = (__bf16)a;
  t[1] = (__bf16)b;
  return __builtin_bit_cast(u32, t);
}

#define SEQ 2048
#define CH  1024
#define NH  16
#define HD  64
// log2(e) / sqrt(64) folded into stored Q so softmax uses exp2
#define QSCALE 0.18033688011112042f

// ------------- fused prep: cast x + transpose-cast qkv_w + proj_w -------------
__global__ void __launch_bounds__(256) prep_kernel(const float* __restrict__ x,
                                                   const float* __restrict__ qkv_w,
                                                   const float* __restrict__ proj_w,
                                                   u16* __restrict__ xb,
                                                   u16* __restrict__ wqkvt,
                                                   u16* __restrict__ wprojt) {
  __shared__ u16 t[64][68];
  int bx = blockIdx.x;
  int tx = threadIdx.x;
  if (bx < 4096) {
    int i = bx * 256 + tx;
    float4 v = ((const float4*)x)[i];
    ushort4 o;
    o.x = f2bf(v.x); o.y = f2bf(v.y); o.z = f2bf(v.z); o.w = f2bf(v.w);
    ((ushort4*)xb)[i] = o;
    return;
  }
  const float* in; u16* out; int R, C, c0, r0;
  if (bx < 4096 + 768) {
    int i = bx - 4096;
    in = qkv_w; out = wqkvt; R = 1024; C = 3072;
    c0 = (i % 48) * 64; r0 = (i / 48) * 64;
  } else {
    int i = bx - 4864;
    in = proj_w; out = wprojt; R = 1024; C = 1024;
    c0 = (i % 16) * 64; r0 = (i / 16) * 64;
  }
  int rr = tx >> 6, cc = tx & 63;
#pragma unroll
  for (int i = 0; i < 16; ++i) {
    int r = i * 4 + rr;
    t[r][cc] = f2bf(in[(size_t)(r0 + r) * C + c0 + cc]);
  }
  __syncthreads();
#pragma unroll
  for (int i = 0; i < 16; ++i) {
    int r = i * 4 + rr;
    out[(size_t)(c0 + r) * R + r0 + cc] = t[cc][r];
  }
}

// ------------- GEMM v3: BK=64, XOR-swizzled LDS, TRUE double-buffered staging -------------
// Stage-after-barrier pattern (validated in attn): DMA of tile t+1 flies during
// compute of tile t, drained only at the next barrier. One barrier per K-iteration.
// mode 0 (qkv): cols<1024 scaled+bf16->qk (stride 2048); cols 1024..2047 bf16->qk;
//               cols>=2048 are V -> written TRANSPOSED to vtout (ushort4 per lane).
// mode 1 (proj): fp32 -> outf.
template <int MT>
__global__ void __launch_bounds__(256) gemm_kernel(const u16* __restrict__ A,
                                                   const u16* __restrict__ Bt,
                                                   const float* __restrict__ bias,
                                                   u16* __restrict__ qk,
                                                   u16* __restrict__ vtout,
                                                   float* __restrict__ outf,
                                                   int K, int mode) {
  constexpr int R = MT * 32;
  __shared__ alignas(16) u16 As[2][R * 64];
  __shared__ alignas(16) u16 Bs[2][128 * 64];
  int tid = threadIdx.x;
  int lane = tid & 63, wave = tid >> 6;
  int wm = wave >> 1, wn = wave & 1;
  int qr = lane & 15, quad = lane >> 4;
  size_t rowA = (size_t)blockIdx.y * R;
  size_t rowB = (size_t)blockIdx.x * 128;

  int klr = lane >> 3;
  int kcs = (lane & 7) ^ klr;

  f32x4 acc[MT][4];
#pragma unroll
  for (int mt = 0; mt < MT; ++mt)
#pragma unroll
    for (int nt = 0; nt < 4; ++nt) acc[mt][nt] = (f32x4){0.f, 0.f, 0.f, 0.f};

  auto stage = [&](int buf, int k0) {
#pragma unroll
    for (int i = 0; i < R / 32; ++i) {
      int ar = wave * (R / 4) + i * 8;
      ASYNC16(A + (rowA + ar + klr) * K + k0 + kcs * 8, &As[buf][ar * 64 + lane * 8]);
    }
#pragma unroll
    for (int i = 0; i < 4; ++i) {
      int br = wave * 32 + i * 8;
      ASYNC16(Bt + (rowB + br + klr) * K + k0 + kcs * 8, &Bs[buf][br * 64 + lane * 8]);
    }
  };

  stage(0, 0);
  int iters = K >> 6;
  for (int t = 0; t < iters; ++t) {
    int cur = t & 1;
    __syncthreads();  // drains DMA into buf[cur]; all waves done reading buf[cur^1]
    if (t + 1 < iters) stage(cur ^ 1, (t + 1) * 64);
#pragma unroll
    for (int ks = 0; ks < 2; ++ks) {
      bf16x8 af[MT], bfr[4];
#pragma unroll
      for (int mt = 0; mt < MT; ++mt) {
        int row = wm * (MT * 16) + mt * 16 + qr;
        af[mt] = *(const bf16x8*)&As[cur][row * 64 + (((ks * 4 + quad) ^ (qr & 7)) << 3)];
      }
#pragma unroll
      for (int nt = 0; nt < 4; ++nt) {
        int row = wn * 64 + nt * 16 + qr;
        bfr[nt] = *(const bf16x8*)&Bs[cur][row * 64 + (((ks * 4 + quad) ^ (qr & 7)) << 3)];
      }
#pragma unroll
      for (int mt = 0; mt < MT; ++mt)
#pragma unroll
        for (int nt = 0; nt < 4; ++nt)
          acc[mt][nt] = MFMA16(af[mt], bfr[nt], acc[mt][nt]);
    }
    __syncthreads();  // reads of buf[cur] done before next iter's stage overwrites
  }

#pragma unroll
  for (int nt = 0; nt < 4; ++nt) {
    int col = (int)rowB + wn * 64 + nt * 16 + qr;
    float bv = bias[col];
#pragma unroll
    for (int mt = 0; mt < MT; ++mt) {
      size_t row = rowA + wm * (MT * 16) + mt * 16 + quad * 4;
      if (mode == 1) {
#pragma unroll
        for (int r = 0; r < 4; ++r)
          outf[(row + r) * 1024 + col] = acc[mt][nt][r] + bv;
      } else if (col < 2048) {
        // Q (scaled) and K -> packed QK buffer, stride 2048
#pragma unroll
        for (int r = 0; r < 4; ++r) {
          float v = acc[mt][nt][r] + bv;
          if (col < 1024) v *= QSCALE;
          qk[(row + r) * 2048 + col] = f2bf(v);
        }
      } else {
        // V -> transposed layout vt[bh][d][n]; 4 accumulator rows = consecutive n
        int c = col - 2048;
        int bh_ = ((int)(row >> 11)) * 16 + (c >> 6);
        int d = c & 63;
        int n = (int)(row & 2047);
        ushort4 pv;
        pv.x = f2bf(acc[mt][nt][0] + bv);
        pv.y = f2bf(acc[mt][nt][1] + bv);
        pv.z = f2bf(acc[mt][nt][2] + bv);
        pv.w = f2bf(acc[mt][nt][3] + bv);
        *(ushort4*)&vtout[(size_t)bh_ * 131072 + d * 2048 + n] = pv;
      }
    }
  }
}

// ------------- flash attention v7: 64-query blocks, KV tile 64, 40KB LDS -------------
// Occupancy fix: previous version (128q x 128kv, 80KB LDS) capped at 2 blocks/CU =
// 2 waves/SIMD -> serialized QK->exp->P->PV chain left MfmaUtil at 27%.
// Now: 64-query blocks (grid 1024), KV tile 64/iter, LDS = 16K(k)+16K(v)+8K(p)
// = 40KB -> 4 blocks/CU = 4 waves/SIMD. Each wave owns 16 query rows.
// QK^T transposed (A=K, B=Q); denominator on the MFMA pipe via B=ones.
// s_setprio(1) wraps the MFMA clusters (T5; pays off with multi-block residency).
__global__ void __launch_bounds__(256) attn_kernel(const u16* __restrict__ qkbuf,
                                                   const u16* __restrict__ vt,
                                                   u16* __restrict__ out) {
  __shared__ alignas(16) u16 kbuf[2][64 * 64];
  __shared__ alignas(16) u16 vbuf[2][64 * 64];
  __shared__ alignas(16) u16 pbuf[4][16 * 64];
  int bh = blockIdx.x;
  int b = bh >> 4, h = bh & 15;
  int m0 = blockIdx.y * 64;
  int tid = threadIdx.x;
  int lane = tid & 63, wave = tid >> 6;
  int qr = lane & 15, quad = lane >> 4;

  const u16* kbase = qkbuf + (size_t)(b * SEQ) * 2048 + 1024 + h * 64;  // K rows, stride 2048
  const u16* vtbase = vt + (size_t)bh * 64 * SEQ;                       // Vt rows, stride 2048
  u16* pw = &pbuf[wave][0];

  int klr = lane >> 3;
  int kcs = (lane & 7) ^ klr;

  // ---- Q fragments (16 rows per wave) ----
  const u16* qbase = qkbuf + (size_t)(b * SEQ + m0 + wave * 16) * 2048 + h * 64;
  bf16x8 qf[2];
#pragma unroll
  for (int ks = 0; ks < 2; ++ks)
    qf[ks] = *(const bf16x8*)&qbase[(size_t)qr * 2048 + ks * 32 + quad * 8];

  const bf16x8 vone = __builtin_bit_cast(bf16x8, (u16x8v)((u16)0x3F80));

  f32x4 o[4], l5;
  l5 = (f32x4){0.f, 0.f, 0.f, 0.f};
#pragma unroll
  for (int dt = 0; dt < 4; ++dt) o[dt] = (f32x4){0.f, 0.f, 0.f, 0.f};

  auto stage = [&](int buf, int n0) {
#pragma unroll
    for (int i = 0; i < 2; ++i) {
      int kr = wave * 16 + i * 8 + klr;
      ASYNC16(kbase + (size_t)(n0 + kr) * 2048 + kcs * 8,
              &kbuf[buf][(wave * 16 + i * 8) * 64 + lane * 8]);
    }
#pragma unroll
    for (int i = 0; i < 2; ++i) {
      int vr = wave * 16 + i * 8 + klr;
      ASYNC16(vtbase + (size_t)vr * 2048 + n0 + kcs * 8,
              &vbuf[buf][(wave * 16 + i * 8) * 64 + lane * 8]);
    }
  };

  stage(0, 0);

  for (int t = 0; t < 32; ++t) {
    int cur = t & 1;
    __syncthreads();  // drains DMA into buf[cur]

    if (t + 1 < 32) stage(cur ^ 1, (t + 1) * 64);

    const u16* kb = &kbuf[cur][0];
    const u16* vb = &vbuf[cur][0];

    bf16x8 kf[4][2];
#pragma unroll
    for (int nt = 0; nt < 4; ++nt)
#pragma unroll
      for (int ks = 0; ks < 2; ++ks)
        kf[nt][ks] =
            *(const bf16x8*)&kb[(nt * 16 + qr) * 64 + (((ks * 4 + quad) ^ (qr & 7)) << 3)];

#pragma unroll
    for (int nt = 0; nt < 4; ++nt) {
      f32x4 z = (f32x4){0.f, 0.f, 0.f, 0.f};
      __builtin_amdgcn_s_setprio(1);
      z = MFMA16(kf[nt][0], qf[0], z);
      z = MFMA16(kf[nt][1], qf[1], z);
      __builtin_amdgcn_s_setprio(0);
      float p0 = __builtin_amdgcn_exp2f(z[0]);
      float p1 = __builtin_amdgcn_exp2f(z[1]);
      float p2 = __builtin_amdgcn_exp2f(z[2]);
      float p3 = __builtin_amdgcn_exp2f(z[3]);
      uint2 pk;
      pk.x = cvt2(p0, p1);
      pk.y = cvt2(p2, p3);
      int nb = nt * 16 + quad * 4;
      int addr = qr * 64 + ((((nb >> 3) ^ (qr & 7)) << 3) | (nb & 7));
      *(uint2*)&pw[addr] = pk;
    }

    bf16x8 vf[4][2];
#pragma unroll
    for (int dt = 0; dt < 4; ++dt)
#pragma unroll
      for (int ks = 0; ks < 2; ++ks)
        vf[dt][ks] =
            *(const bf16x8*)&vb[(dt * 16 + qr) * 64 + (((ks * 4 + quad) ^ (qr & 7)) << 3)];

    bf16x8 pf[2];
#pragma unroll
    for (int ks = 0; ks < 2; ++ks)
      pf[ks] = *(const bf16x8*)&pw[qr * 64 + (((ks * 4 + quad) ^ (qr & 7)) << 3)];

    __builtin_amdgcn_s_setprio(1);
#pragma unroll
    for (int dt = 0; dt < 4; ++dt) {
      o[dt] = MFMA16(pf[0], vf[dt][0], o[dt]);
      o[dt] = MFMA16(pf[1], vf[dt][1], o[dt]);
    }
    l5 = MFMA16(pf[0], vone, l5);
    l5 = MFMA16(pf[1], vone, l5);
    __builtin_amdgcn_s_setprio(0);

    __syncthreads();  // reads of buf[cur] done before next iter's stage overwrites
  }

  u16* obase = out + (size_t)(b * SEQ + m0 + wave * 16) * CH + h * 64;
#pragma unroll
  for (int r = 0; r < 4; ++r) {
    float inv = 1.0f / l5[r];
#pragma unroll
    for (int dt = 0; dt < 4; ++dt)
      obase[(size_t)(quad * 4 + r) * CH + dt * 16 + qr] = f2bf(o[dt][r] * inv);
  }
}

extern "C" void kernel_launch(void* const* d_in, const int* in_sizes, int n_in,
                              void* d_out, int out_size, void* d_ws, size_t ws_size,
                              hipStream_t stream) {
  const float* x      = (const float*)d_in[0];
  const float* qkv_w  = (const float*)d_in[1];
  const float* qkv_b  = (const float*)d_in[2];
  const float* proj_w = (const float*)d_in[3];
  const float* proj_b = (const float*)d_in[4];
  float* out = (float*)d_out;

  char* w = (char*)d_ws;
  // ws layout (42 MB):
  //   qkqk  : 4096x2048 bf16 (Q scaled | K, stride 2048) = 16777216 B
  //   xb    : 4096x1024 bf16 = 8388608 B (reused as attn_bf after gemm1)
  //   wprojt: 1024x1024 bf16 = 2097152 B
  //   wqkvt : 3072x1024 bf16 = 6291456 B
  //   vt    : (B*H)x64x2048 bf16 = 8388608 B (written directly by gemm1 epilogue)
  u16* qkqk   = (u16*)w;
  u16* xb     = (u16*)(w + 16777216);
  u16* wprojt = (u16*)(w + 25165824);
  u16* wqkvt  = (u16*)(w + 27262976);
  u16* vt     = (u16*)(w + 33554432);
  u16* attn_bf = xb;

  prep_kernel<<<5120, 256, 0, stream>>>(x, qkv_w, proj_w, xb, wqkvt, wprojt);
  // qkv = x @ qkv_w + b; Q scaled; QK -> qkqk (stride 2048), V -> vt (transposed)
  gemm_kernel<4><<<dim3(24, 32), 256, 0, stream>>>(xb, wqkvt, qkv_b, qkqk, vt, nullptr, 1024, 0);
  attn_kernel<<<dim3(32, 32), 256, 0, stream>>>(qkqk, vt, attn_bf);
  // out = attn @ proj_w + b (fp32)
  gemm_kernel<2><<<dim3(8, 64), 256, 0, stream>>>(attn_bf, wprojt, proj_b, nullptr, nullptr, out, 1024, 1);
}

// Round 2
// 179.914 us; speedup vs baseline: 1.1237x; 1.1237x over previous
//
#include <hip/hip_runtime.h>
#include <cstdint>
#include <cstddef>

typedef __bf16 bf16x8 __attribute__((ext_vector_type(8)));
typedef __bf16 bf16x2v __attribute__((ext_vector_type(2)));
typedef unsigned short u16;
typedef u16 u16x8v __attribute__((ext_vector_type(8)));
typedef float  f32x4  __attribute__((ext_vector_type(4)));
typedef unsigned int u32;

#define MFMA16(a, b, c) __builtin_amdgcn_mfma_f32_16x16x32_bf16((a), (b), (c), 0, 0, 0)
#define ASYNC16(g, l)                                                              \
  __builtin_amdgcn_global_load_lds(                                                \
      (const __attribute__((address_space(1))) unsigned int*)(g),                  \
      (__attribute__((address_space(3))) unsigned int*)(l), 16, 0, 0)

__device__ __forceinline__ u16 f2bf(float f) {
  unsigned u = __builtin_bit_cast(unsigned, f);
  u += 0x7fffu + ((u >> 16) & 1u);
  return (u16)(u >> 16);
}

// packed fp32x2 -> bf16x2 (RNE) via hardware cvt
__device__ __forceinline__ u32 cvt2(float a, float b) {
  bf16x2v t;
  t[0] = (__bf16)a;
  t[1] = (__bf16)b;
  return __builtin_bit_cast(u32, t);
}

#define SEQ 2048
#define CH  1024
#define NH  16
#define HD  64
// log2(e) / sqrt(64) folded into stored Q so softmax uses exp2
#define QSCALE 0.18033688011112042f

// ------------- fused prep: cast x + transpose-cast qkv_w + proj_w -------------
__global__ void __launch_bounds__(256) prep_kernel(const float* __restrict__ x,
                                                   const float* __restrict__ qkv_w,
                                                   const float* __restrict__ proj_w,
                                                   u16* __restrict__ xb,
                                                   u16* __restrict__ wqkvt,
                                                   u16* __restrict__ wprojt) {
  __shared__ u16 t[64][68];
  int bx = blockIdx.x;
  int tx = threadIdx.x;
  if (bx < 4096) {
    int i = bx * 256 + tx;
    float4 v = ((const float4*)x)[i];
    ushort4 o;
    o.x = f2bf(v.x); o.y = f2bf(v.y); o.z = f2bf(v.z); o.w = f2bf(v.w);
    ((ushort4*)xb)[i] = o;
    return;
  }
  const float* in; u16* out; int R, C, c0, r0;
  if (bx < 4096 + 768) {
    int i = bx - 4096;
    in = qkv_w; out = wqkvt; R = 1024; C = 3072;
    c0 = (i % 48) * 64; r0 = (i / 48) * 64;
  } else {
    int i = bx - 4864;
    in = proj_w; out = wprojt; R = 1024; C = 1024;
    c0 = (i % 16) * 64; r0 = (i / 16) * 64;
  }
  int rr = tx >> 6, cc = tx & 63;
#pragma unroll
  for (int i = 0; i < 16; ++i) {
    int r = i * 4 + rr;
    t[r][cc] = f2bf(in[(size_t)(r0 + r) * C + c0 + cc]);
  }
  __syncthreads();
#pragma unroll
  for (int i = 0; i < 16; ++i) {
    int r = i * 4 + rr;
    out[(size_t)(c0 + r) * R + r0 + cc] = t[cc][r];
  }
}

// ------------- GEMM v4: BK=64, XOR-swizzled LDS, double-buffered staging,
//               COALESCED EPILOGUE via LDS restage -------------
// Main loop unchanged from v3 (known-good). Epilogue change: instead of 64
// scalar 2B/4B global stores per thread (QK path) or scattered 8B stores at
// 4KB stride (V-transpose path), the output tile is staged into the now-idle
// 64KB of LDS (padded strides: 136 u16 / 132 f32 -> 16B-aligned rows, ~2-way
// banks) and written out as fully-coalesced 16B stores (256B per 16 lanes).
// mode 0 (qkv): cols<1024 scaled+bf16->qk; 1024..2047 bf16->qk (stride 2048);
//               cols>=2048 are V -> vt[bh][d][n] transposed, coalesced along n.
// mode 1 (proj): fp32 -> outf.
template <int MT>
__global__ void __launch_bounds__(256) gemm_kernel(const u16* __restrict__ A,
                                                   const u16* __restrict__ Bt,
                                                   const float* __restrict__ bias,
                                                   u16* __restrict__ qk,
                                                   u16* __restrict__ vtout,
                                                   float* __restrict__ outf,
                                                   int K, int mode) {
  constexpr int R = MT * 32;
  __shared__ alignas(16) u16 smem[2 * R * 64 + 2 * 128 * 64];
  auto As = (u16(*)[R * 64])smem;
  auto Bs = (u16(*)[128 * 64])(smem + 2 * R * 64);
  int tid = threadIdx.x;
  int lane = tid & 63, wave = tid >> 6;
  int wm = wave >> 1, wn = wave & 1;
  int qr = lane & 15, quad = lane >> 4;
  size_t rowA = (size_t)blockIdx.y * R;
  size_t rowB = (size_t)blockIdx.x * 128;

  int klr = lane >> 3;
  int kcs = (lane & 7) ^ klr;

  f32x4 acc[MT][4];
#pragma unroll
  for (int mt = 0; mt < MT; ++mt)
#pragma unroll
    for (int nt = 0; nt < 4; ++nt) acc[mt][nt] = (f32x4){0.f, 0.f, 0.f, 0.f};

  auto stage = [&](int buf, int k0) {
#pragma unroll
    for (int i = 0; i < R / 32; ++i) {
      int ar = wave * (R / 4) + i * 8;
      ASYNC16(A + (rowA + ar + klr) * K + k0 + kcs * 8, &As[buf][ar * 64 + lane * 8]);
    }
#pragma unroll
    for (int i = 0; i < 4; ++i) {
      int br = wave * 32 + i * 8;
      ASYNC16(Bt + (rowB + br + klr) * K + k0 + kcs * 8, &Bs[buf][br * 64 + lane * 8]);
    }
  };

  stage(0, 0);
  int iters = K >> 6;
  for (int t = 0; t < iters; ++t) {
    int cur = t & 1;
    __syncthreads();  // drains DMA into buf[cur]; all waves done reading buf[cur^1]
    if (t + 1 < iters) stage(cur ^ 1, (t + 1) * 64);
#pragma unroll
    for (int ks = 0; ks < 2; ++ks) {
      bf16x8 af[MT], bfr[4];
#pragma unroll
      for (int mt = 0; mt < MT; ++mt) {
        int row = wm * (MT * 16) + mt * 16 + qr;
        af[mt] = *(const bf16x8*)&As[cur][row * 64 + (((ks * 4 + quad) ^ (qr & 7)) << 3)];
      }
#pragma unroll
      for (int nt = 0; nt < 4; ++nt) {
        int row = wn * 64 + nt * 16 + qr;
        bfr[nt] = *(const bf16x8*)&Bs[cur][row * 64 + (((ks * 4 + quad) ^ (qr & 7)) << 3)];
      }
#pragma unroll
      for (int mt = 0; mt < MT; ++mt)
#pragma unroll
        for (int nt = 0; nt < 4; ++nt)
          acc[mt][nt] = MFMA16(af[mt], bfr[nt], acc[mt][nt]);
    }
    __syncthreads();  // reads of buf[cur] done before next iter's stage overwrites
  }

  __syncthreads();  // compute done; smem reusable for epilogue staging

  if (mode == 1) {
    // fp32 tile [R][128], padded stride 132 floats (528B, 16B-aligned rows)
    float* epf = (float*)smem;
#pragma unroll
    for (int nt = 0; nt < 4; ++nt) {
      int cl = wn * 64 + nt * 16 + qr;
      float bv = bias[rowB + cl];
#pragma unroll
      for (int mt = 0; mt < MT; ++mt) {
        int rl = wm * (MT * 16) + mt * 16 + quad * 4;
#pragma unroll
        for (int r = 0; r < 4; ++r)
          epf[(rl + r) * 132 + cl] = acc[mt][nt][r] + bv;
      }
    }
    __syncthreads();
    int rr = wave * 2 + (lane >> 5);
    int cc = (lane & 31) * 4;
#pragma unroll
    for (int p = 0; p < R / 8; ++p) {
      int row = p * 8 + rr;
      float4 v = *(const float4*)&epf[row * 132 + cc];
      *(float4*)&outf[(rowA + row) * 1024 + rowB + cc] = v;
    }
  } else if ((int)rowB < 2048) {
    // Q (scaled) / K -> packed QK buffer (stride 2048), coalesced 16B stores
    float sc = ((int)rowB < 1024) ? QSCALE : 1.0f;  // whole 128-col tile is Q or K
    u16* ep = smem;  // [R][128] u16, padded stride 136 (272B, 16B-aligned rows)
#pragma unroll
    for (int nt = 0; nt < 4; ++nt) {
      int cl = wn * 64 + nt * 16 + qr;
      float bv = bias[rowB + cl];
#pragma unroll
      for (int mt = 0; mt < MT; ++mt) {
        int rl = wm * (MT * 16) + mt * 16 + quad * 4;
#pragma unroll
        for (int r = 0; r < 4; ++r)
          ep[(rl + r) * 136 + cl] = f2bf((acc[mt][nt][r] + bv) * sc);
      }
    }
    __syncthreads();
    int rr = wave * 4 + (lane >> 4);
    int cc = (lane & 15) * 8;
#pragma unroll
    for (int p = 0; p < R / 16; ++p) {
      int row = p * 16 + rr;
      u16x8v v = *(const u16x8v*)&ep[row * 136 + cc];
      *(u16x8v*)&qk[(rowA + row) * 2048 + rowB + cc] = v;
    }
  } else {
    // V -> vt[bh][d][n]: stage transposed tile [d][n] in LDS, then write
    // coalesced 256B rows along n.
    u16* ep = smem;  // [128 d][R n] u16, padded stride 136
#pragma unroll
    for (int nt = 0; nt < 4; ++nt) {
      int cl = wn * 64 + nt * 16 + qr;  // d_local 0..127
      float bv = bias[rowB + cl];
#pragma unroll
      for (int mt = 0; mt < MT; ++mt) {
        int rl = wm * (MT * 16) + mt * 16 + quad * 4;  // n_local, multiple of 4
        ushort4 pv;
        pv.x = f2bf(acc[mt][nt][0] + bv);
        pv.y = f2bf(acc[mt][nt][1] + bv);
        pv.z = f2bf(acc[mt][nt][2] + bv);
        pv.w = f2bf(acc[mt][nt][3] + bv);
        *(ushort4*)&ep[cl * 136 + rl] = pv;
      }
    }
    __syncthreads();
    int batch = (int)(rowA >> 11);
    int n_base = (int)(rowA & 2047);
    int rr = wave * 4 + (lane >> 4);
    int cc = (lane & 15) * 8;
#pragma unroll
    for (int p = 0; p < 8; ++p) {
      int d = p * 16 + rr;                      // 0..127 (2 heads x 64)
      int cglob = (int)rowB - 2048 + d;
      int bh_ = batch * 16 + (cglob >> 6);
      u16x8v v = *(const u16x8v*)&ep[d * 136 + cc];
      *(u16x8v*)&vtout[(size_t)bh_ * 131072 + (size_t)(cglob & 63) * 2048 + n_base + cc] = v;
    }
  }
}

// ------------- flash attention v6 (round-0 best), QK stride 2048 -------------
// K-tile (128x64) + Vt-tile (64x128) DMA'd to LDS (global_load_lds 16B, chunk-XOR
// swizzle), double-buffered: 64KB. One barrier per 128 keys (16 total).
// QK^T transposed (A=K, B=Q); denominator on the MFMA pipe via B=ones.
// NOTE round-1 experiment: halving tiles to raise occupancy (32%) LOWERED
// MfmaUtil (27->23) and raised dur (56->64.5) -- attn is per-barrier-work
// bound, not TLP bound. Keep the 36-MFMA-per-barrier structure.
__global__ void __launch_bounds__(256) attn_kernel(const u16* __restrict__ qkbuf,
                                                   const u16* __restrict__ vt,
                                                   u16* __restrict__ out) {
  __shared__ alignas(16) u16 kbuf[2][128 * 64];
  __shared__ alignas(16) u16 vbuf[2][64 * 128];
  __shared__ alignas(16) u16 pbuf[4][32 * 64];
  int bh = blockIdx.x;
  int b = bh >> 4, h = bh & 15;
  int m0 = blockIdx.y * 128;
  int tid = threadIdx.x;
  int lane = tid & 63, wave = tid >> 6;
  int qr = lane & 15, quad = lane >> 4;

  const u16* kbase = qkbuf + (size_t)(b * SEQ) * 2048 + 1024 + h * 64;  // K rows, stride 2048
  const u16* vtbase = vt + (size_t)bh * 64 * SEQ;                       // Vt rows, stride 2048
  u16* pw = &pbuf[wave][0];

  int klr = lane >> 3;
  int kcs = (lane & 7) ^ klr;

  // ---- Q fragments (32 rows per wave) ----
  const u16* qbase = qkbuf + (size_t)(b * SEQ + m0 + wave * 32) * 2048 + h * 64;
  bf16x8 qf[2][2];
#pragma unroll
  for (int mt = 0; mt < 2; ++mt)
#pragma unroll
    for (int ks = 0; ks < 2; ++ks)
      qf[mt][ks] = *(const bf16x8*)&qbase[(size_t)(mt * 16 + qr) * 2048 + ks * 32 + quad * 8];

  const bf16x8 vone = __builtin_bit_cast(bf16x8, (u16x8v)((u16)0x3F80));

  f32x4 o[2][4], l5[2];
#pragma unroll
  for (int mt = 0; mt < 2; ++mt) {
    l5[mt] = (f32x4){0.f, 0.f, 0.f, 0.f};
#pragma unroll
    for (int dt = 0; dt < 4; ++dt) o[mt][dt] = (f32x4){0.f, 0.f, 0.f, 0.f};
  }

  auto stage = [&](int buf, int n0) {
#pragma unroll
    for (int i = 0; i < 4; ++i) {
      int kr = wave * 32 + i * 8 + klr;
      ASYNC16(kbase + (size_t)(n0 + kr) * 2048 + kcs * 8,
              &kbuf[buf][(wave * 32 + i * 8) * 64 + lane * 8]);
    }
#pragma unroll
    for (int i = 0; i < 4; ++i) {
      int vr = wave * 16 + i * 4 + (lane >> 4);
      int vcs = ((lane & 7) ^ (vr & 7)) | (lane & 8);
      ASYNC16(vtbase + (size_t)vr * 2048 + n0 + vcs * 8,
              &vbuf[buf][(wave * 16 + i * 4) * 128 + lane * 8]);
    }
  };

  stage(0, 0);

  for (int t = 0; t < 16; ++t) {
    int cur = t & 1;
    __syncthreads();

    if (t + 1 < 16) stage(cur ^ 1, (t + 1) * 128);

#pragma unroll
    for (int sp = 0; sp < 2; ++sp) {
      const u16* kb = &kbuf[cur][sp * 64 * 64];
      const u16* vb = &vbuf[cur][0];

      bf16x8 kf[4][2];
#pragma unroll
      for (int nt = 0; nt < 4; ++nt)
#pragma unroll
        for (int ks = 0; ks < 2; ++ks)
          kf[nt][ks] =
              *(const bf16x8*)&kb[(nt * 16 + qr) * 64 + (((ks * 4 + quad) ^ (qr & 7)) << 3)];

#pragma unroll
      for (int mt = 0; mt < 2; ++mt)
#pragma unroll
        for (int nt = 0; nt < 4; ++nt) {
          f32x4 z = (f32x4){0.f, 0.f, 0.f, 0.f};
          z = MFMA16(kf[nt][0], qf[mt][0], z);
          z = MFMA16(kf[nt][1], qf[mt][1], z);
          float p0 = __builtin_amdgcn_exp2f(z[0]);
          float p1 = __builtin_amdgcn_exp2f(z[1]);
          float p2 = __builtin_amdgcn_exp2f(z[2]);
          float p3 = __builtin_amdgcn_exp2f(z[3]);
          uint2 pk;
          pk.x = cvt2(p0, p1);
          pk.y = cvt2(p2, p3);
          int nb = nt * 16 + quad * 4;
          int addr = (mt * 16 + qr) * 64 + ((((nb >> 3) ^ (qr & 7)) << 3) | (nb & 7));
          *(uint2*)&pw[addr] = pk;
        }

      bf16x8 vf[4][2];
#pragma unroll
      for (int dt = 0; dt < 4; ++dt)
#pragma unroll
        for (int ks = 0; ks < 2; ++ks)
          vf[dt][ks] = *(const bf16x8*)&vb[(dt * 16 + qr) * 128 +
                                           ((sp * 8 + ((ks * 4 + quad) ^ (qr & 7))) << 3)];

      bf16x8 pf[2][2];
#pragma unroll
      for (int mt = 0; mt < 2; ++mt)
#pragma unroll
        for (int ks = 0; ks < 2; ++ks)
          pf[mt][ks] =
              *(const bf16x8*)&pw[(mt * 16 + qr) * 64 + (((ks * 4 + quad) ^ (qr & 7)) << 3)];

#pragma unroll
      for (int mt = 0; mt < 2; ++mt) {
#pragma unroll
        for (int dt = 0; dt < 4; ++dt) {
          o[mt][dt] = MFMA16(pf[mt][0], vf[dt][0], o[mt][dt]);
          o[mt][dt] = MFMA16(pf[mt][1], vf[dt][1], o[mt][dt]);
        }
        l5[mt] = MFMA16(pf[mt][0], vone, l5[mt]);
        l5[mt] = MFMA16(pf[mt][1], vone, l5[mt]);
      }
    }
  }

  u16* obase = out + (size_t)(b * SEQ + m0 + wave * 32) * CH + h * 64;
#pragma unroll
  for (int mt = 0; mt < 2; ++mt)
#pragma unroll
    for (int r = 0; r < 4; ++r) {
      float inv = 1.0f / l5[mt][r];
#pragma unroll
      for (int dt = 0; dt < 4; ++dt)
        obase[(size_t)(mt * 16 + quad * 4 + r) * CH + dt * 16 + qr] = f2bf(o[mt][dt][r] * inv);
    }
}

extern "C" void kernel_launch(void* const* d_in, const int* in_sizes, int n_in,
                              void* d_out, int out_size, void* d_ws, size_t ws_size,
                              hipStream_t stream) {
  const float* x      = (const float*)d_in[0];
  const float* qkv_w  = (const float*)d_in[1];
  const float* qkv_b  = (const float*)d_in[2];
  const float* proj_w = (const float*)d_in[3];
  const float* proj_b = (const float*)d_in[4];
  float* out = (float*)d_out;

  char* w = (char*)d_ws;
  // ws layout (42 MB):
  //   qkqk  : 4096x2048 bf16 (Q scaled | K, stride 2048) = 16777216 B
  //   xb    : 4096x1024 bf16 = 8388608 B (reused as attn_bf after gemm1)
  //   wprojt: 1024x1024 bf16 = 2097152 B
  //   wqkvt : 3072x1024 bf16 = 6291456 B
  //   vt    : (B*H)x64x2048 bf16 = 8388608 B (written directly by gemm1 epilogue)
  u16* qkqk   = (u16*)w;
  u16* xb     = (u16*)(w + 16777216);
  u16* wprojt = (u16*)(w + 25165824);
  u16* wqkvt  = (u16*)(w + 27262976);
  u16* vt     = (u16*)(w + 33554432);
  u16* attn_bf = xb;

  prep_kernel<<<5120, 256, 0, stream>>>(x, qkv_w, proj_w, xb, wqkvt, wprojt);
  // qkv = x @ qkv_w + b; Q scaled; QK -> qkqk (stride 2048), V -> vt (transposed)
  gemm_kernel<4><<<dim3(24, 32), 256, 0, stream>>>(xb, wqkvt, qkv_b, qkqk, vt, nullptr, 1024, 0);
  attn_kernel<<<dim3(32, 16), 256, 0, stream>>>(qkqk, vt, attn_bf);
  // out = attn @ proj_w + b (fp32)
  gemm_kernel<2><<<dim3(8, 64), 256, 0, stream>>>(attn_bf, wprojt, proj_b, nullptr, nullptr, out, 1024, 1);
}